// Round 1
// baseline (349.122 us; speedup 1.0000x reference)
//
#include <hip/hip_runtime.h>
#include <hip/hip_bf16.h>
#include <math.h>

#define NP 10      // planets
#define NE 45      // edges per timestep
#define TS 16      // timesteps per block (100000 / 16 = 6250 exact)
#define BLOCK 256
#define H 32       // hidden width

__device__ __forceinline__ float rcp_fast(float x) { return __builtin_amdgcn_rcpf(x); }

__device__ __forceinline__ float tanh_fast(float x) {
    // tanh(x) = (e^{2x}-1)/(e^{2x}+1); clamp so exp stays finite in fp32
    x = fminf(20.0f, fmaxf(-20.0f, x));
    float e = __expf(2.0f * x);
    return (e - 1.0f) * rcp_fast(e + 1.0f);
}

__global__ __launch_bounds__(BLOCK) void
learn_forces_kernel(const float* __restrict__ D_V,
                    const float* __restrict__ logm,
                    const float* __restrict__ W1, const float* __restrict__ b1,
                    const float* __restrict__ W2, const float* __restrict__ b2,
                    const float* __restrict__ W3, const float* __restrict__ b3,
                    const int* __restrict__ senders, const int* __restrict__ receivers,
                    float* __restrict__ out, int ntime)
{
    __shared__ float slm[NP];
    __shared__ int   ssnd[NE];
    __shared__ int   srcv[NE];
    __shared__ float acc[TS * NP * 3];

    const int tid = threadIdx.x;
    if (tid < NP) slm[tid] = fminf(12.0f, fmaxf(-12.0f, logm[tid]));
    if (tid < NE) { ssnd[tid] = senders[tid]; srcv[tid] = receivers[tid]; }
    for (int i = tid; i < TS * NP * 3; i += BLOCK) acc[i] = 0.0f;
    __syncthreads();

    const long t0 = (long)blockIdx.x * TS;

    for (int idx = tid; idx < TS * NE; idx += BLOCK) {
        int lt = idx / NE;          // local timestep
        int le = idx - lt * NE;     // edge within timestep
        long t = t0 + lt;
        if (t >= ntime) break;      // tail guard (exact for 100000)

        const float* dv = D_V + ((long)t * NE + le) * 3;
        float x = dv[0], y = dv[1], z = dv[2];

        // cart -> sph
        float r  = sqrtf(x * x + y * y + z * z);
        float zr = z * rcp_fast(r);
        zr = fminf(1.0f, fmaxf(-1.0f, zr));
        float theta = acosf(zr);
        float phi   = atan2f(y, x);

        int si = ssnd[le], ri = srcv[le];
        float f[5] = { r, theta, phi, slm[ri], slm[si] };

        // MLP layer 1: 5 -> 32 (weights via wave-uniform indices -> s_load)
        float h1[H];
        #pragma unroll
        for (int j = 0; j < H; ++j) {
            float a = b1[j];
            #pragma unroll
            for (int k = 0; k < 5; ++k) a = fmaf(f[k], W1[k * H + j], a);
            h1[j] = tanh_fast(a);
        }

        // layer 2: 32 -> 32
        float h2[H];
        #pragma unroll
        for (int j = 0; j < H; ++j) {
            float a = b2[j];
            #pragma unroll
            for (int k = 0; k < H; ++k) a = fmaf(h1[k], W2[k * H + j], a);
            h2[j] = tanh_fast(a);
        }

        // layer 3: 32 -> 3 (linear)
        float e0 = b3[0], e1 = b3[1], e2 = b3[2];
        #pragma unroll
        for (int k = 0; k < H; ++k) {
            e0 = fmaf(h2[k], W3[k * 3 + 0], e0);
            e1 = fmaf(h2[k], W3[k * 3 + 1], e1);
            e2 = fmaf(h2[k], W3[k * 3 + 2], e2);
        }

        // sph -> cart: e = [r', theta', phi']
        float st = __sinf(e1), ct = __cosf(e1);
        float sp = __sinf(e2), cp = __cosf(e2);
        float ex = e0 * st * cp;
        float ey = e0 * st * sp;
        float ez = e0 * ct;

        // scatter: +receiver, -sender (LDS atomics; timestep owned by this block)
        float* ar = &acc[(lt * NP + ri) * 3];
        float* as = &acc[(lt * NP + si) * 3];
        atomicAdd(&ar[0],  ex); atomicAdd(&ar[1],  ey); atomicAdd(&ar[2],  ez);
        atomicAdd(&as[0], -ex); atomicAdd(&as[1], -ey); atomicAdd(&as[2], -ez);
    }
    __syncthreads();

    // accel = forces / exp(lm_clip[p]); coalesced write
    for (int i = tid; i < TS * NP * 3; i += BLOCK) {
        long t = t0 + i / (NP * 3);
        if (t >= ntime) continue;
        int p = (i / 3) % NP;
        out[t0 * NP * 3 + i] = acc[i] * __expf(-slm[p]);
    }
}

extern "C" void kernel_launch(void* const* d_in, const int* in_sizes, int n_in,
                              void* d_out, int out_size, void* d_ws, size_t ws_size,
                              hipStream_t stream) {
    const float* D_V  = (const float*)d_in[0];
    const float* logm = (const float*)d_in[1];
    const float* W1   = (const float*)d_in[2];
    const float* b1   = (const float*)d_in[3];
    const float* W2   = (const float*)d_in[4];
    const float* b2   = (const float*)d_in[5];
    const float* W3   = (const float*)d_in[6];
    const float* b3   = (const float*)d_in[7];
    const int* senders   = (const int*)d_in[8];
    const int* receivers = (const int*)d_in[9];

    int nedges = in_sizes[8];                 // 45
    int ntime  = in_sizes[0] / 3 / nedges;    // 100000

    int nblocks = (ntime + TS - 1) / TS;
    learn_forces_kernel<<<nblocks, BLOCK, 0, stream>>>(
        D_V, logm, W1, b1, W2, b2, W3, b3, senders, receivers,
        (float*)d_out, ntime);
}

// Round 2
// 307.010 us; speedup vs baseline: 1.1372x; 1.1372x over previous
//
#include <hip/hip_runtime.h>
#include <hip/hip_bf16.h>
#include <math.h>

#define NP 10
#define NE 45
#define TS 16                 // timesteps per block
#define EPB (TS * NE)         // 720 edges per block
#define BLOCK 256
#define NCHUNK 12             // ceil(720/64); 3 chunks per wave

typedef __attribute__((ext_vector_type(8))) short short8;   // 8 bf16 MFMA frag
typedef __attribute__((ext_vector_type(4))) float f32x4;    // MFMA acc

#define C2LOG2E 2.885390081777927f   // 2*log2(e), folded into W1/W2/b1/b2

__device__ __forceinline__ float rcp_fast(float x) { return __builtin_amdgcn_rcpf(x); }

// input prescaled by 2*log2(e): tanh(a) = 1 - 2/(2^s + 1); self-saturating, no clamp
__device__ __forceinline__ float tanh_pre(float s) {
    float e = __builtin_amdgcn_exp2f(s);
    return fmaf(-2.0f, rcp_fast(e + 1.0f), 1.0f);
}

// RNE bf16 (setup-time, precision matters for weights)
__device__ __forceinline__ short bf16_rne(float f) {
    unsigned int u = __float_as_uint(f);
    return (short)((u + 0x7fffu + ((u >> 16) & 1u)) >> 16);
}
// fast round-half-up pack of two floats -> bf16x2 (activations)
__device__ __forceinline__ int bf16pk(float a, float b) {
    unsigned int ua = __float_as_uint(a) + 0x8000u;
    unsigned int ub = __float_as_uint(b) + 0x8000u;
    return (int)((ua >> 16) | (ub & 0xffff0000u));
}

__global__ __launch_bounds__(BLOCK) void
learn_forces_kernel(const float* __restrict__ D_V, const float* __restrict__ logm,
                    const float* __restrict__ W1, const float* __restrict__ b1,
                    const float* __restrict__ W2, const float* __restrict__ b2,
                    const float* __restrict__ W3, const float* __restrict__ b3,
                    const int* __restrict__ senders, const int* __restrict__ receivers,
                    float* __restrict__ out, int ntime)
{
    __shared__ float slm[NP];
    __shared__ int   ssnd[NE], srcv[NE];
    __shared__ float acc[TS * NP * 3];                     // 1.92 KB
    __shared__ __align__(16) short feat_s[4][64 * 8];      // 4 KB  : 8 bf16/edge
    __shared__ __align__(16) short h_s[4][64 * 40];        // 20 KB : 80B rows (32 bf16 + pad)
    __shared__ float e3_s[4][64 * 3];                      // 3 KB

    const int tid  = threadIdx.x;
    const int wv   = tid >> 6, lane = tid & 63;
    const int m    = lane & 15, q = lane >> 4;

    if (tid < NP) slm[tid] = fminf(12.0f, fmaxf(-12.0f, logm[tid]));
    if (tid < NE) { ssnd[tid] = senders[tid]; srcv[tid] = receivers[tid]; }
    for (int i = tid; i < TS * NP * 3; i += BLOCK) acc[i] = 0.0f;

    // ---- A fragments: A[mrow][k] = W[k][mrow], lane holds k = 8q+j, mrow = m (+16*tile)
    short8 a1[2], a2[2], a3f;
    float  b1v[8], b2v[8], b3r[4];
    for (int t = 0; t < 2; ++t)
        for (int j = 0; j < 8; ++j) {
            int k = 8 * q + j;
            a1[t][j] = (k < 5) ? bf16_rne(W1[k * 32 + m + 16 * t] * C2LOG2E) : (short)0;
            a2[t][j] = bf16_rne(W2[k * 32 + m + 16 * t] * C2LOG2E);
        }
    for (int j = 0; j < 8; ++j)
        a3f[j] = (m < 3) ? bf16_rne(W3[(8 * q + j) * 3 + m]) : (short)0;
    for (int t = 0; t < 2; ++t)
        for (int r = 0; r < 4; ++r) {
            b1v[t * 4 + r] = b1[16 * t + 4 * q + r] * C2LOG2E;
            b2v[t * 4 + r] = b2[16 * t + 4 * q + r] * C2LOG2E;
        }
    for (int r = 0; r < 4; ++r) {
        int row = 4 * q + r;
        b3r[r] = (row < 3) ? b3[row] : 0.0f;
    }

    __syncthreads();

    short* feat = feat_s[wv];
    short* hbuf = h_s[wv];
    float* e3   = e3_s[wv];
    const f32x4 zf = {0.f, 0.f, 0.f, 0.f};

    for (int c = wv; c < NCHUNK; c += 4) {
        int  e_blk  = c * 64 + lane;
        bool active = e_blk < EPB;
        int  le = e_blk % NE;
        int  lt = e_blk / NE;
        int  si = ssnd[le], ri = srcv[le];

        float x = 0.f, y = 0.f, z = 1.f;     // inactive lanes: (0,0,1) -> no NaN
        if (active) {
            const float* dv = D_V + ((long)blockIdx.x * EPB + e_blk) * 3;
            x = dv[0]; y = dv[1]; z = dv[2];
        }
        float r  = sqrtf(x * x + y * y + z * z);
        float zr = fminf(1.0f, fmaxf(-1.0f, z * rcp_fast(r)));
        float th = acosf(zr);
        float ph = atan2f(y, x);
        float f3 = slm[ri], f4 = slm[si];

        // stage features as bf16 B-rows (k=0..4 real, rest 0)
        int* frow = (int*)&feat[lane * 8];
        frow[0] = bf16pk(r,  th);
        frow[1] = bf16pk(ph, f3);
        frow[2] = bf16pk(f4, 0.f);
        frow[3] = 0;

        // ---- layer 1: 5->32 (K=32 padded; only q==0 lanes carry nonzero B) ----
        #pragma unroll
        for (int g = 0; g < 4; ++g) {
            short8 bf = 0;
            if (q == 0) bf = *(const short8*)&feat[(16 * g + m) * 8];
            f32x4 d0 = __builtin_amdgcn_mfma_f32_16x16x32_bf16(a1[0], bf, zf, 0, 0, 0);
            f32x4 d1 = __builtin_amdgcn_mfma_f32_16x16x32_bf16(a1[1], bf, zf, 0, 0, 0);
            int* hrow = (int*)&hbuf[(16 * g + m) * 40];
            float t0 = tanh_pre(d0[0] + b1v[0]), t1 = tanh_pre(d0[1] + b1v[1]);
            float t2 = tanh_pre(d0[2] + b1v[2]), t3 = tanh_pre(d0[3] + b1v[3]);
            float u0 = tanh_pre(d1[0] + b1v[4]), u1 = tanh_pre(d1[1] + b1v[5]);
            float u2 = tanh_pre(d1[2] + b1v[6]), u3 = tanh_pre(d1[3] + b1v[7]);
            hrow[q * 2 + 0]     = bf16pk(t0, t1);
            hrow[q * 2 + 1]     = bf16pk(t2, t3);
            hrow[8 + q * 2 + 0] = bf16pk(u0, u1);
            hrow[8 + q * 2 + 1] = bf16pk(u2, u3);
        }

        // ---- layer 2: 32->32 (read h1 rows of group g, overwrite with h2: in-order DS) ----
        #pragma unroll
        for (int g = 0; g < 4; ++g) {
            short8 bf = *(const short8*)&hbuf[(16 * g + m) * 40 + q * 8];
            f32x4 d0 = __builtin_amdgcn_mfma_f32_16x16x32_bf16(a2[0], bf, zf, 0, 0, 0);
            f32x4 d1 = __builtin_amdgcn_mfma_f32_16x16x32_bf16(a2[1], bf, zf, 0, 0, 0);
            int* hrow = (int*)&hbuf[(16 * g + m) * 40];
            float t0 = tanh_pre(d0[0] + b2v[0]), t1 = tanh_pre(d0[1] + b2v[1]);
            float t2 = tanh_pre(d0[2] + b2v[2]), t3 = tanh_pre(d0[3] + b2v[3]);
            float u0 = tanh_pre(d1[0] + b2v[4]), u1 = tanh_pre(d1[1] + b2v[5]);
            float u2 = tanh_pre(d1[2] + b2v[6]), u3 = tanh_pre(d1[3] + b2v[7]);
            hrow[q * 2 + 0]     = bf16pk(t0, t1);
            hrow[q * 2 + 1]     = bf16pk(t2, t3);
            hrow[8 + q * 2 + 0] = bf16pk(u0, u1);
            hrow[8 + q * 2 + 1] = bf16pk(u2, u3);
        }

        // ---- layer 3: 32->3 (rows 0..2 live in q==0 lanes) ----
        #pragma unroll
        for (int g = 0; g < 4; ++g) {
            short8 bf = *(const short8*)&hbuf[(16 * g + m) * 40 + q * 8];
            f32x4 d = __builtin_amdgcn_mfma_f32_16x16x32_bf16(a3f, bf, zf, 0, 0, 0);
            if (q == 0) {
                float* er = &e3[(16 * g + m) * 3];
                er[0] = d[0] + b3r[0];
                er[1] = d[1] + b3r[1];
                er[2] = d[2] + b3r[2];
            }
        }

        // ---- per-edge epilogue: sph->cart + signed scatter ----
        float e0 = e3[lane * 3 + 0], e1 = e3[lane * 3 + 1], e2 = e3[lane * 3 + 2];
        float st = __sinf(e1), ct = __cosf(e1);
        float sp = __sinf(e2), cp = __cosf(e2);
        float ex = e0 * st * cp, ey = e0 * st * sp, ez = e0 * ct;
        if (active) {
            float* ar = &acc[(lt * NP + ri) * 3];
            float* as = &acc[(lt * NP + si) * 3];
            atomicAdd(&ar[0],  ex); atomicAdd(&ar[1],  ey); atomicAdd(&ar[2],  ez);
            atomicAdd(&as[0], -ex); atomicAdd(&as[1], -ey); atomicAdd(&as[2], -ez);
        }
    }
    __syncthreads();

    const long t0g = (long)blockIdx.x * TS;
    for (int i = tid; i < TS * NP * 3; i += BLOCK) {
        int p = (i / 3) % NP;
        out[t0g * NP * 3 + i] = acc[i] * __expf(-slm[p]);
    }
}

extern "C" void kernel_launch(void* const* d_in, const int* in_sizes, int n_in,
                              void* d_out, int out_size, void* d_ws, size_t ws_size,
                              hipStream_t stream) {
    const float* D_V  = (const float*)d_in[0];
    const float* logm = (const float*)d_in[1];
    const float* W1   = (const float*)d_in[2];
    const float* b1   = (const float*)d_in[3];
    const float* W2   = (const float*)d_in[4];
    const float* b2   = (const float*)d_in[5];
    const float* W3   = (const float*)d_in[6];
    const float* b3   = (const float*)d_in[7];
    const int* senders   = (const int*)d_in[8];
    const int* receivers = (const int*)d_in[9];

    int nedges = in_sizes[8];               // 45
    int ntime  = in_sizes[0] / 3 / nedges;  // 100000

    int nblocks = (ntime + TS - 1) / TS;    // 6250
    learn_forces_kernel<<<nblocks, BLOCK, 0, stream>>>(
        D_V, logm, W1, b1, W2, b2, W3, b3, senders, receivers,
        (float*)d_out, ntime);
}